// Round 15
// baseline (152.128 us; speedup 1.0000x reference)
//
#include <hip/hip_runtime.h>
#include <hip/hip_bf16.h>

#define EPS 1e-5f

typedef __attribute__((ext_vector_type(8))) short bf16x8;
typedef __attribute__((ext_vector_type(4))) float f32x4;

__device__ __forceinline__ void gload16(const void* g, void* l) {
  __builtin_amdgcn_global_load_lds(
      (const __attribute__((address_space(1))) unsigned int*)g,
      (__attribute__((address_space(3))) unsigned int*)l, 16, 0, 0);
}

// truncation-based hi/lo bf16 split
__device__ __forceinline__ void split2(float x, short& h, short& l) {
  unsigned u = __float_as_uint(x);
  h = (short)(u >> 16);
  float hf = __uint_as_float(u & 0xFFFF0000u);
  l = (short)(__float_as_uint(x - hf) >> 16);
}
__device__ __forceinline__ void bn_coef(float s, float q, float g, float be,
                                        float& sc, float& sh) {
  float mu = s * (1.f / 2048.f);
  float var = q * (1.f / 2048.f) - mu * mu;
  sc = g * rsqrtf(var + EPS);
  sh = be - mu * sc;
}

// ---------------- kpre: all input-only prep in ONE launch ----------------
// grid 1489: [0,1024) W2 hi/lo trunc-split tiled-swizzled | [1024,1029) zero stats |
//            [1029,1189) W3 split hi/lo | [1189,1489) zero Y3
__global__ __launch_bounds__(256) void kpre(
    const float* __restrict__ W2, const float* __restrict__ W3,
    ushort* __restrict__ W2thi, ushort* __restrict__ W2tlo,
    ushort* __restrict__ W3hi, ushort* __restrict__ W3lo,
    float4* __restrict__ stv, float4* __restrict__ Y3v) {
  int b = blockIdx.x;
  int tid = threadIdx.x;
  if (b < 1024) {
    int c = tid * 4;
    int nt = b >> 6, rr = b & 63;
    int kt = c >> 6, chunk = (c >> 3) & 7, e = c & 7;
    float4 v = *(const float4*)&W2[(size_t)b * 1024 + c];
    float ev[4] = {v.x, v.y, v.z, v.w};
    short hh[4], ll[4];
#pragma unroll
    for (int q = 0; q < 4; ++q) split2(ev[q], hh[q], ll[q]);
    size_t o = ((size_t)(nt * 16 + kt) << 12) + rr * 64 + ((chunk ^ (rr & 7)) << 3) + e;
    *(ushort4*)&W2thi[o] = make_ushort4((ushort)hh[0], (ushort)hh[1],
                                        (ushort)hh[2], (ushort)hh[3]);
    *(ushort4*)&W2tlo[o] = make_ushort4((ushort)ll[0], (ushort)ll[1],
                                        (ushort)ll[2], (ushort)ll[3]);
  } else if (b < 1029) {
    int idx = (b - 1024) * 256 + tid;
    if (idx < 1112) stv[idx] = make_float4(0.f, 0.f, 0.f, 0.f);
  } else if (b < 1189) {
    int n = b - 1029;
    int c = tid * 4;
    float4 v = make_float4(0.f, 0.f, 0.f, 0.f);
    if (n < 150) v = *(const float4*)&W3[(size_t)n * 1024 + c];
    float e[4] = {v.x, v.y, v.z, v.w};
    short hh[4], ll[4];
#pragma unroll
    for (int q = 0; q < 4; ++q) split2(e[q], hh[q], ll[q]);
    *(ushort4*)&W3hi[(size_t)n * 1024 + c] =
        make_ushort4((ushort)hh[0], (ushort)hh[1], (ushort)hh[2], (ushort)hh[3]);
    *(ushort4*)&W3lo[(size_t)n * 1024 + c] =
        make_ushort4((ushort)ll[0], (ushort)ll[1], (ushort)ll[2], (ushort)ll[3]);
  } else {
    Y3v[(b - 1189) * 256 + tid] = make_float4(0.f, 0.f, 0.f, 0.f);
  }
}

// ---------------- k1s: layer1 raw stats -> atomic accumulators ----------------
__global__ __launch_bounds__(256) void k1s(const float* __restrict__ G,
                                           const float* __restrict__ W1,
                                           float* __restrict__ sA1,
                                           float* __restrict__ qA1) {
  int r0 = blockIdx.x * 8;
  int c = threadIdx.x * 4;
  float w[4][8];
#pragma unroll
  for (int q = 0; q < 4; ++q)
#pragma unroll
    for (int k = 0; k < 8; ++k) w[q][k] = W1[(c + q) * 8 + k];
  float s[4] = {}, ss[4] = {};
  for (int r = 0; r < 8; ++r) {
    const float4 g0 = *(const float4*)&G[(size_t)(r0 + r) * 8];
    const float4 g1 = *(const float4*)&G[(size_t)(r0 + r) * 8 + 4];
    float gr[8] = {g0.x, g0.y, g0.z, g0.w, g1.x, g1.y, g1.z, g1.w};
#pragma unroll
    for (int q = 0; q < 4; ++q) {
      float acc = 0.f;
#pragma unroll
      for (int k = 0; k < 8; ++k) acc += gr[k] * w[q][k];
      s[q] += acc;
      ss[q] += acc * acc;
    }
  }
#pragma unroll
  for (int q = 0; q < 4; ++q) {
    atomicAdd(&sA1[c + q], s[q]);
    atomicAdd(&qA1[c + q], ss[q]);
  }
}

// ---------------- k1c: raw Y1, BN1+ReLU, split, write TILED-SWIZZLED ----------------
__global__ __launch_bounds__(256) void k1c(
    const float* __restrict__ G, const float* __restrict__ W1,
    const float* __restrict__ sA1, const float* __restrict__ qA1,
    const float* __restrict__ g1, const float* __restrict__ be1,
    ushort* __restrict__ X1thi, ushort* __restrict__ X1tlo) {
  int r0 = blockIdx.x * 8;
  int c = threadIdx.x * 4;
  float w[4][8];
#pragma unroll
  for (int q = 0; q < 4; ++q)
#pragma unroll
    for (int k = 0; k < 8; ++k) w[q][k] = W1[(c + q) * 8 + k];
  float sc[4], sh[4];
#pragma unroll
  for (int q = 0; q < 4; ++q)
    bn_coef(sA1[c + q], qA1[c + q], g1[c + q], be1[c + q], sc[q], sh[q]);
  int kt = c >> 6, chunk = (c >> 3) & 7, e = c & 7;
  for (int r = 0; r < 8; ++r) {
    int b = r0 + r;
    const float4 g0 = *(const float4*)&G[(size_t)b * 8];
    const float4 g1v = *(const float4*)&G[(size_t)b * 8 + 4];
    float gr[8] = {g0.x, g0.y, g0.z, g0.w, g1v.x, g1v.y, g1v.z, g1v.w};
    short hs[4], ls[4];
#pragma unroll
    for (int q = 0; q < 4; ++q) {
      float acc = 0.f;
#pragma unroll
      for (int k = 0; k < 8; ++k) acc += gr[k] * w[q][k];
      float x = fmaxf(0.f, acc * sc[q] + sh[q]);
      split2(x, hs[q], ls[q]);
    }
    int mt = b >> 7, rr = b & 127;
    size_t o = ((size_t)(mt * 16 + kt) << 13) + rr * 64 + ((chunk ^ (rr & 7)) << 3) + e;
    *(ushort4*)&X1thi[o] = make_ushort4((ushort)hs[0], (ushort)hs[1],
                                        (ushort)hs[2], (ushort)hs[3]);
    *(ushort4*)&X1tlo[o] = make_ushort4((ushort)ls[0], (ushort)ls[1],
                                        (ushort)ls[2], (ushort)ls[3]);
  }
}

// ---------------- k2: MFMA GEMM2 (3-term), gload_lds staging, fused stats ----------------
__global__ __launch_bounds__(512) void k2_mfma(
    const ushort* __restrict__ X1thi, const ushort* __restrict__ X1tlo,
    const ushort* __restrict__ W2thi, const ushort* __restrict__ W2tlo,
    float* __restrict__ Y2, float* __restrict__ sA2, float* __restrict__ qA2) {
  __shared__ short lAhi[128 * 64], lAlo[128 * 64];
  __shared__ short lBhi[64 * 64], lBlo[64 * 64];
  int id = blockIdx.x;
  int xcd = id & 7, slot = id >> 3;
  int g = slot >> 4, wi = slot & 15;
  int bx = (xcd & 3) * 4 + (wi & 3);
  int by = ((xcd >> 2) * 2 + g) * 4 + (wi >> 2);
  int b0 = bx * 128, j0 = by * 64;
  int tid = threadIdx.x;
  int lane = tid & 63, wave = tid >> 6;
  int wm = wave >> 1, wn = wave & 1;
  int woff = wave * 1024 + lane * 16;
  int loff = wave * 1024;
  f32x4 acc[2][2] = {};
  for (int kt = 0; kt < 16; ++kt) {
    const char* ga = (const char*)(X1thi + ((size_t)(bx * 16 + kt) << 13));
    const char* gl = (const char*)(X1tlo + ((size_t)(bx * 16 + kt) << 13));
    const char* gb = (const char*)(W2thi + ((size_t)(by * 16 + kt) << 12));
    const char* gc = (const char*)(W2tlo + ((size_t)(by * 16 + kt) << 12));
    gload16(ga + woff, (char*)lAhi + loff);
    gload16(ga + woff + 8192, (char*)lAhi + loff + 8192);
    gload16(gl + woff, (char*)lAlo + loff);
    gload16(gl + woff + 8192, (char*)lAlo + loff + 8192);
    gload16(gb + woff, (char*)lBhi + loff);
    gload16(gc + woff, (char*)lBlo + loff);
    __syncthreads();
#pragma unroll
    for (int kk = 0; kk < 2; ++kk) {
      int ch = kk * 4 + (lane >> 4);
      bf16x8 ah[2], al[2], bh[2], bl[2];
#pragma unroll
      for (int mi = 0; mi < 2; ++mi) {
        int rr = wm * 32 + mi * 16 + (lane & 15);
        int ad = rr * 64 + ((ch ^ (rr & 7)) << 3);
        ah[mi] = *(const bf16x8*)&lAhi[ad];
        al[mi] = *(const bf16x8*)&lAlo[ad];
      }
#pragma unroll
      for (int ni = 0; ni < 2; ++ni) {
        int rr = wn * 32 + ni * 16 + (lane & 15);
        int bd = rr * 64 + ((ch ^ (rr & 7)) << 3);
        bh[ni] = *(const bf16x8*)&lBhi[bd];
        bl[ni] = *(const bf16x8*)&lBlo[bd];
      }
#pragma unroll
      for (int mi = 0; mi < 2; ++mi)
#pragma unroll
        for (int ni = 0; ni < 2; ++ni) {
          acc[mi][ni] = __builtin_amdgcn_mfma_f32_16x16x32_bf16(
              ah[mi], bh[ni], acc[mi][ni], 0, 0, 0);
          acc[mi][ni] = __builtin_amdgcn_mfma_f32_16x16x32_bf16(
              al[mi], bh[ni], acc[mi][ni], 0, 0, 0);
          acc[mi][ni] = __builtin_amdgcn_mfma_f32_16x16x32_bf16(
              ah[mi], bl[ni], acc[mi][ni], 0, 0, 0);
        }
    }
    __syncthreads();
  }
#pragma unroll
  for (int mi = 0; mi < 2; ++mi)
#pragma unroll
    for (int ni = 0; ni < 2; ++ni) {
      int col = j0 + wn * 32 + ni * 16 + (lane & 15);
#pragma unroll
      for (int r = 0; r < 4; ++r) {
        int row = b0 + wm * 32 + mi * 16 + (lane >> 4) * 4 + r;
        Y2[(size_t)row * 1024 + col] = acc[mi][ni][r];
      }
    }
#pragma unroll
  for (int ni = 0; ni < 2; ++ni) {
    float s = 0.f, q = 0.f;
#pragma unroll
    for (int mi = 0; mi < 2; ++mi)
#pragma unroll
      for (int r = 0; r < 4; ++r) {
        float v = acc[mi][ni][r];
        s += v;
        q += v * v;
      }
    s += __shfl_xor(s, 16);
    q += __shfl_xor(q, 16);
    s += __shfl_xor(s, 32);
    q += __shfl_xor(q, 32);
    if ((lane >> 4) == 0) {
      int col = j0 + wn * 32 + ni * 16 + lane;
      atomicAdd(&sA2[col], s);
      atomicAdd(&qA2[col], q);
    }
  }
}

// ---------------- k4: MFMA GEMM3, inline BN2 coefs + ReLU, atomic into Y3 ----------------
__global__ __launch_bounds__(256) void k4_mfma(
    const float* __restrict__ Y2, const float* __restrict__ sA2,
    const float* __restrict__ qA2, const float* __restrict__ g2,
    const float* __restrict__ be2, const ushort* __restrict__ W3hi,
    const ushort* __restrict__ W3lo, float* __restrict__ Y3) {
  __shared__ short lAhi[32 * 64], lAlo[32 * 64];
  int b0 = blockIdx.x * 32;
  int kb = blockIdx.y * 128;
  int tid = threadIdx.x;
  int lane = tid & 63, wave = tid >> 6;
  int wm = wave & 1, wn = wave >> 1;
  f32x4 acc[5] = {};
  int srow = tid >> 3, sch = tid & 7;
  for (int k0 = 0; k0 < 128; k0 += 64) {
    int kg = kb + k0 + sch * 8;
    const float* src = &Y2[(size_t)(b0 + srow) * 1024 + kg];
    float4 f0 = *(const float4*)src;
    float4 f1 = *(const float4*)(src + 4);
    float4 sv0 = *(const float4*)&sA2[kg];
    float4 sv1 = *(const float4*)&sA2[kg + 4];
    float4 qv0 = *(const float4*)&qA2[kg];
    float4 qv1 = *(const float4*)&qA2[kg + 4];
    float4 gv0 = *(const float4*)&g2[kg];
    float4 gv1 = *(const float4*)&g2[kg + 4];
    float4 bv0 = *(const float4*)&be2[kg];
    float4 bv1 = *(const float4*)&be2[kg + 4];
    float e[8] = {f0.x, f0.y, f0.z, f0.w, f1.x, f1.y, f1.z, f1.w};
    float sv[8] = {sv0.x, sv0.y, sv0.z, sv0.w, sv1.x, sv1.y, sv1.z, sv1.w};
    float qv[8] = {qv0.x, qv0.y, qv0.z, qv0.w, qv1.x, qv1.y, qv1.z, qv1.w};
    float gv[8] = {gv0.x, gv0.y, gv0.z, gv0.w, gv1.x, gv1.y, gv1.z, gv1.w};
    float bev[8] = {bv0.x, bv0.y, bv0.z, bv0.w, bv1.x, bv1.y, bv1.z, bv1.w};
    bf16x8 hh, ll;
#pragma unroll
    for (int q = 0; q < 8; ++q) {
      float sc, sh;
      bn_coef(sv[q], qv[q], gv[q], bev[q], sc, sh);
      float x = fmaxf(0.f, fmaf(e[q], sc, sh));
      short h, l;
      split2(x, h, l);
      hh[q] = h;
      ll[q] = l;
    }
    if (k0) __syncthreads();
    int d = srow * 64 + ((sch ^ (srow & 7)) << 3);
    *(bf16x8*)&lAhi[d] = hh;
    *(bf16x8*)&lAlo[d] = ll;
    __syncthreads();
#pragma unroll
    for (int kk = 0; kk < 2; ++kk) {
      int r = wm * 16 + (lane & 15);
      int ch = kk * 4 + (lane >> 4);
      int ad = r * 64 + ((ch ^ (r & 7)) << 3);
      bf16x8 ah = *(const bf16x8*)&lAhi[ad];
      bf16x8 al = *(const bf16x8*)&lAlo[ad];
#pragma unroll
      for (int ni = 0; ni < 5; ++ni) {
        int col = wn * 80 + ni * 16 + (lane & 15);
        size_t wo = (size_t)col * 1024 + kb + k0 + kk * 32 + (lane >> 4) * 8;
        bf16x8 bh = *(const bf16x8*)&W3hi[wo];
        bf16x8 bl = *(const bf16x8*)&W3lo[wo];
        acc[ni] = __builtin_amdgcn_mfma_f32_16x16x32_bf16(ah, bh, acc[ni], 0, 0, 0);
        acc[ni] = __builtin_amdgcn_mfma_f32_16x16x32_bf16(al, bh, acc[ni], 0, 0, 0);
        acc[ni] = __builtin_amdgcn_mfma_f32_16x16x32_bf16(ah, bl, acc[ni], 0, 0, 0);
      }
    }
  }
#pragma unroll
  for (int ni = 0; ni < 5; ++ni) {
    int col = wn * 80 + ni * 16 + (lane & 15);
    if (col < 150) {
#pragma unroll
      for (int r = 0; r < 4; ++r) {
        int row = b0 + wm * 16 + (lane >> 4) * 4 + r;
        atomicAdd(&Y3[(size_t)row * 150 + col], acc[ni][r]);
      }
    }
  }
}

// ---------------- k5s: raw Y3 column stats -> atomic accumulators ----------------
__global__ __launch_bounds__(256) void k5s(const float* __restrict__ Y3,
                                           float* __restrict__ sA3,
                                           float* __restrict__ qA3) {
  int r0 = blockIdx.x * 8;
  int j = threadIdx.x;
  if (j >= 150) return;
  float s = 0.f, q = 0.f;
  for (int r = 0; r < 8; ++r) {
    float v = Y3[(size_t)(r0 + r) * 150 + j];
    s += v;
    q += v * v;
  }
  atomicAdd(&sA3[j], s);
  atomicAdd(&qA3[j], q);
}

// ---------------- k6a: BN3+ReLU + ct1 + composite conv -> lorentz rational coefs ----------------
// Spre per (r,cc): q0={c1,c2,A,B}, q1={nC,0,0,0}
//   D(x)=x^2+c1*x+c2 ; n^2*D = A - B*x ; kap2*D = B*x + nC   (x = w^2)
__global__ __launch_bounds__(256) void k6a(
    const float* __restrict__ Y3, const float* __restrict__ sA3,
    const float* __restrict__ qA3, const float* __restrict__ g3,
    const float* __restrict__ be3, const float* __restrict__ ct1_w,
    const float* __restrict__ ct1_b, const float* __restrict__ ct2_w,
    const float* __restrict__ ct2_b, const float* __restrict__ ct3_w,
    const float* __restrict__ ct3_b, const float* __restrict__ cf_w,
    const float* __restrict__ cf_b, float* __restrict__ Spre) {
  __shared__ float wt1[32], wb1[4], wt2L[80], wb2L[4], w3fL[20];
  __shared__ float Cc[36], cfb2C[1], cfbraw[1];
  __shared__ float h0p[4][160];
  __shared__ float hA[4][4][312];
  __shared__ float Srow[4][304];
  int tid = threadIdx.x;
  if (tid < 32) wt1[tid] = ct1_w[tid];
  else if (tid < 36) wb1[tid - 32] = ct1_b[tid - 32];
  else if (tid < 116) wt2L[tid - 36] = ct2_w[tid - 36];
  else if (tid < 120) wb2L[tid - 116] = ct2_b[tid - 116];
  else if (tid < 140) {
    int i = (tid - 120) / 5, j = (tid - 120) % 5;
    float s = 0.f;
#pragma unroll
    for (int p = 0; p < 4; ++p) s += cf_w[p] * ct3_w[(i * 4 + p) * 5 + j];
    w3fL[tid - 120] = s;
  } else if (tid == 140) {
    float s = cf_b[0];
#pragma unroll
    for (int p = 0; p < 4; ++p) s += cf_w[p] * ct3_b[p];
    cfbraw[0] = s;
  }
  int w = tid >> 6;
  int lane = tid & 63;
  int r = blockIdx.x * 4 + w;
  for (int i = lane; i < 160; i += 64) {
    int k = i - 2;
    float v = 0.f;
    if (k >= 0 && k < 150) {
      float sc, sh;
      bn_coef(sA3[k], qA3[k], g3[k], be3[k], sc, sh);
      v = fmaxf(0.f, Y3[(size_t)r * 150 + k] * sc + sh);
    }
    h0p[w][i] = v;
  }
  if (lane < 12) {
    int z = (lane < 4) ? lane : (300 + lane);
#pragma unroll
    for (int o = 0; o < 4; ++o) hA[w][o][z] = 0.f;
  }
  __syncthreads();
  if (tid < 36) {
    int i = tid / 9, u = tid % 9;
    float s = 0.f;
#pragma unroll
    for (int o = 0; o < 4; ++o) {
      int j2lo = (u > 4) ? (u - 4) : 0;
      int j2hi = (u < 4) ? u : 4;
      for (int j2 = j2lo; j2 <= j2hi; ++j2)
        s += wt2L[(i * 4 + o) * 5 + (u - j2)] * w3fL[o * 5 + j2];
    }
    Cc[tid] = s;
  } else if (tid == 36) {
    float s = cfbraw[0];
#pragma unroll
    for (int o = 0; o < 4; ++o) {
      float t = 0.f;
#pragma unroll
      for (int j2 = 0; j2 < 5; ++j2) t += w3fL[o * 5 + j2];
      s += wb2L[o] * t;
    }
    cfb2C[0] = s;
  }
  __syncthreads();
  for (int t = lane; t < 300; t += 64) {
    int p1 = (t + 3) & 1;
    int base = (t + 3 - p1) >> 1;
    float x0 = h0p[w][2 + base];
    float x1 = h0p[w][1 + base];
    float x2 = h0p[w][base];
    float x3 = h0p[w][base - 1];
#pragma unroll
    for (int o = 0; o < 4; ++o) {
      float acc = wb1[o];
      acc += wt1[o * 8 + p1] * x0;
      acc += wt1[o * 8 + p1 + 2] * x1;
      acc += wt1[o * 8 + p1 + 4] * x2;
      acc += wt1[o * 8 + p1 + 6] * x3;
      hA[w][o][4 + t] = acc;
    }
  }
  __syncthreads();
  for (int t = lane; t < 300; t += 64) {
    float acc = cfb2C[0];
#pragma unroll
    for (int i = 0; i < 4; ++i)
#pragma unroll
      for (int u = 0; u < 9; ++u) acc += Cc[i * 9 + u] * hA[w][i][t + 8 - u];
    if (t < 2) {
      for (int j2 = t + 3; j2 <= 4; ++j2) {
        int tp_ = t + 2 - j2;
        float corr = 0.f;
        for (int o = 0; o < 4; ++o) {
          float hb = wb2L[o];
          for (int i2 = 0; i2 < 4; ++i2)
            for (int j1 = 0; j1 < 5; ++j1)
              hb += wt2L[(i2 * 4 + o) * 5 + j1] * hA[w][i2][6 + tp_ - j1];
          corr += w3fL[o * 5 + j2] * hb;
        }
        acc -= corr;
      }
    }
    if (t > 297) {
      for (int j2 = 0; j2 <= t - 298; ++j2) {
        int tp_ = t + 2 - j2;
        float corr = 0.f;
        for (int o = 0; o < 4; ++o) {
          float hb = wb2L[o];
          for (int i2 = 0; i2 < 4; ++i2)
            for (int j1 = 0; j1 < 5; ++j1)
              hb += wt2L[(i2 * 4 + o) * 5 + j1] * hA[w][i2][6 + tp_ - j1];
          corr += w3fL[o * 5 + j2] * hb;
        }
        acc -= corr;
      }
    }
    Srow[w][t] = acc;
  }
  __syncthreads();
  for (int cc = lane; cc < 100; cc += 64) {
    float s0 = Srow[w][3 * cc], s1 = Srow[w][3 * cc + 1], s2 = Srow[w][3 * cc + 2];
    float P = s0 * s0, s1s = s1 * s1, s2s = s2 * s2;
    float halfP = 0.5f * P;
    float4 q0, q1;
    q0.x = s2s - 2.f * s1s;       // c1
    q0.y = s1s * s1s;             // c2
    q0.z = halfP * (P + s1s);     // A
    q0.w = halfP;                 // B
    q1.x = halfP * (P - s1s);     // nC
    q1.y = 0.f;
    q1.z = 0.f;
    q1.w = 0.f;
    size_t o = ((size_t)r * 100 + cc) * 8;
    *(float4*)&Spre[o] = q0;
    *(float4*)&Spre[o + 4] = q1;
  }
}

// ---------------- k6b: lorentz, UNSPLIT (100 cc), plain store ----------------
__global__ __launch_bounds__(320) void k6b(const float* __restrict__ Spre,
                                           float* __restrict__ out) {
  int b = blockIdx.x;
  int l = threadIdx.x;
  float wl = 0.8f + (float)l * (1.0f / 300.0f);
  float x = wl * wl;
  float xn = -x;
  float acc = 0.f;
  const float4* pp = (const float4*)(Spre + (size_t)b * 800);
#pragma unroll 5
  for (int cc = 0; cc < 100; ++cc) {
    float4 q0 = pp[2 * cc];      // {c1, c2, A, B}  (uniform addr -> s_load)
    float4 q1 = pp[2 * cc + 1];  // {nC, -, -, -}
    float D = fmaf(x, x + q0.x, q0.y);
    float iv = __builtin_amdgcn_rcpf(D);
    float t1 = fmaf(q0.w, xn, q0.z);
    float t2 = fmaf(q0.w, x, q1.x);
    float n2 = t1 * iv;
    float kp = t2 * iv;
    float n = __builtin_amdgcn_sqrtf(fmaxf(n2, 0.f));
    float np1 = n + 1.f;
    float d2 = fmaf(np1, np1, fmaxf(kp, 0.f));
    acc = fmaf(n, __builtin_amdgcn_rcpf(d2), acc);
  }
  if (l < 300) out[(size_t)b * 300 + l] = 4.0f * acc;
}

extern "C" void kernel_launch(void* const* d_in, const int* in_sizes, int n_in,
                              void* d_out, int out_size, void* d_ws,
                              size_t ws_size, hipStream_t stream) {
  const float* G = (const float*)d_in[0];
  const float* w1 = (const float*)d_in[1];
  const float* g1 = (const float*)d_in[3];
  const float* be1 = (const float*)d_in[4];
  const float* w2 = (const float*)d_in[5];
  const float* g2 = (const float*)d_in[7];
  const float* be2 = (const float*)d_in[8];
  const float* w3 = (const float*)d_in[9];
  const float* g3 = (const float*)d_in[11];
  const float* be3 = (const float*)d_in[12];
  const float* ct1_w = (const float*)d_in[13];
  const float* ct1_b = (const float*)d_in[14];
  const float* ct2_w = (const float*)d_in[15];
  const float* ct2_b = (const float*)d_in[16];
  const float* ct3_w = (const float*)d_in[17];
  const float* ct3_b = (const float*)d_in[18];
  const float* cf_w = (const float*)d_in[19];
  const float* cf_b = (const float*)d_in[20];
  float* out = (float*)d_out;

  float* ws = (float*)d_ws;
  // float-offset layout:
  float* Y2 = ws;                           // [0, 2097152) k2->k4
  float* Spre = ws;                         // same region, after k4 (k6a->k6b, 1638400 f)
  ushort* X1thi = (ushort*)(ws + 2097152);  // [2097152, 3145728) k1c->k2
  ushort* X1tlo = (ushort*)(ws + 3145728);  // [3145728, 4194304) k1c->k2
  float* sA1 = ws + 4194304;                // stats block (4448 floats)
  float* qA1 = sA1 + 1024;
  float* sA2 = sA1 + 2048;
  float* qA2 = sA1 + 3072;
  float* sA3 = sA1 + 4096;
  float* qA3 = sA1 + 4288;
  ushort* W2thi = (ushort*)(ws + 4198752);  // [4198752, 4723040)
  ushort* W2tlo = (ushort*)(ws + 4723040);  // [4723040, 5247328)
  ushort* W3hi = (ushort*)(ws + 5247328);   // [5247328, 5329248)
  ushort* W3lo = (ushort*)(ws + 5329248);   // [5329248, 5411168)
  float* Y3 = ws + 5411168;                 // [5411168, 5718368)

  kpre<<<1489, 256, 0, stream>>>(w2, w3, W2thi, W2tlo, W3hi, W3lo,
                                 (float4*)sA1, (float4*)Y3);
  k1s<<<256, 256, 0, stream>>>(G, w1, sA1, qA1);
  k1c<<<256, 256, 0, stream>>>(G, w1, sA1, qA1, g1, be1, X1thi, X1tlo);
  k2_mfma<<<256, 512, 0, stream>>>(X1thi, X1tlo, W2thi, W2tlo, Y2, sA2, qA2);
  k4_mfma<<<dim3(64, 8), 256, 0, stream>>>(Y2, sA2, qA2, g2, be2, W3hi, W3lo, Y3);
  k5s<<<256, 256, 0, stream>>>(Y3, sA3, qA3);
  k6a<<<512, 256, 0, stream>>>(Y3, sA3, qA3, g3, be3, ct1_w, ct1_b, ct2_w,
                               ct2_b, ct3_w, ct3_b, cf_w, cf_b, Spre);
  k6b<<<2048, 320, 0, stream>>>(Spre, out);
}

// Round 16
// 139.606 us; speedup vs baseline: 1.0897x; 1.0897x over previous
//
#include <hip/hip_runtime.h>
#include <hip/hip_bf16.h>

#define EPS 1e-5f

typedef __attribute__((ext_vector_type(8))) short bf16x8;
typedef __attribute__((ext_vector_type(4))) float f32x4;

__device__ __forceinline__ void gload16(const void* g, void* l) {
  __builtin_amdgcn_global_load_lds(
      (const __attribute__((address_space(1))) unsigned int*)g,
      (__attribute__((address_space(3))) unsigned int*)l, 16, 0, 0);
}

// truncation-based hi/lo bf16 split
__device__ __forceinline__ void split2(float x, short& h, short& l) {
  unsigned u = __float_as_uint(x);
  h = (short)(u >> 16);
  float hf = __uint_as_float(u & 0xFFFF0000u);
  l = (short)(__float_as_uint(x - hf) >> 16);
}
__device__ __forceinline__ void bn_coef(float s, float q, float g, float be,
                                        float& sc, float& sh) {
  float mu = s * (1.f / 2048.f);
  float var = q * (1.f / 2048.f) - mu * mu;
  sc = g * rsqrtf(var + EPS);
  sh = be - mu * sc;
}

// ---------------- kpre: all input-only prep in ONE launch ----------------
// grid 2089: [0,1024) W2 hi/lo trunc-split tiled-swizzled | [1024,1029) zero stats |
//            [1029,1189) W3 split hi/lo | [1189,1489) zero Y3 | [1489,2089) zero out
__global__ __launch_bounds__(256) void kpre(
    const float* __restrict__ W2, const float* __restrict__ W3,
    ushort* __restrict__ W2thi, ushort* __restrict__ W2tlo,
    ushort* __restrict__ W3hi, ushort* __restrict__ W3lo,
    float4* __restrict__ stv, float4* __restrict__ Y3v,
    float4* __restrict__ outv) {
  int b = blockIdx.x;
  int tid = threadIdx.x;
  if (b < 1024) {
    int c = tid * 4;
    int nt = b >> 6, rr = b & 63;
    int kt = c >> 6, chunk = (c >> 3) & 7, e = c & 7;
    float4 v = *(const float4*)&W2[(size_t)b * 1024 + c];
    float ev[4] = {v.x, v.y, v.z, v.w};
    short hh[4], ll[4];
#pragma unroll
    for (int q = 0; q < 4; ++q) split2(ev[q], hh[q], ll[q]);
    size_t o = ((size_t)(nt * 16 + kt) << 12) + rr * 64 + ((chunk ^ (rr & 7)) << 3) + e;
    *(ushort4*)&W2thi[o] = make_ushort4((ushort)hh[0], (ushort)hh[1],
                                        (ushort)hh[2], (ushort)hh[3]);
    *(ushort4*)&W2tlo[o] = make_ushort4((ushort)ll[0], (ushort)ll[1],
                                        (ushort)ll[2], (ushort)ll[3]);
  } else if (b < 1029) {
    int idx = (b - 1024) * 256 + tid;
    if (idx < 1112) stv[idx] = make_float4(0.f, 0.f, 0.f, 0.f);
  } else if (b < 1189) {
    int n = b - 1029;
    int c = tid * 4;
    float4 v = make_float4(0.f, 0.f, 0.f, 0.f);
    if (n < 150) v = *(const float4*)&W3[(size_t)n * 1024 + c];
    float e[4] = {v.x, v.y, v.z, v.w};
    short hh[4], ll[4];
#pragma unroll
    for (int q = 0; q < 4; ++q) split2(e[q], hh[q], ll[q]);
    *(ushort4*)&W3hi[(size_t)n * 1024 + c] =
        make_ushort4((ushort)hh[0], (ushort)hh[1], (ushort)hh[2], (ushort)hh[3]);
    *(ushort4*)&W3lo[(size_t)n * 1024 + c] =
        make_ushort4((ushort)ll[0], (ushort)ll[1], (ushort)ll[2], (ushort)ll[3]);
  } else if (b < 1489) {
    Y3v[(b - 1189) * 256 + tid] = make_float4(0.f, 0.f, 0.f, 0.f);
  } else {
    outv[(b - 1489) * 256 + tid] = make_float4(0.f, 0.f, 0.f, 0.f);
  }
}

// ---------------- k1s: layer1 raw stats -> atomic accumulators ----------------
__global__ __launch_bounds__(256) void k1s(const float* __restrict__ G,
                                           const float* __restrict__ W1,
                                           float* __restrict__ sA1,
                                           float* __restrict__ qA1) {
  int r0 = blockIdx.x * 8;
  int c = threadIdx.x * 4;
  float w[4][8];
#pragma unroll
  for (int q = 0; q < 4; ++q)
#pragma unroll
    for (int k = 0; k < 8; ++k) w[q][k] = W1[(c + q) * 8 + k];
  float s[4] = {}, ss[4] = {};
  for (int r = 0; r < 8; ++r) {
    const float4 g0 = *(const float4*)&G[(size_t)(r0 + r) * 8];
    const float4 g1 = *(const float4*)&G[(size_t)(r0 + r) * 8 + 4];
    float gr[8] = {g0.x, g0.y, g0.z, g0.w, g1.x, g1.y, g1.z, g1.w};
#pragma unroll
    for (int q = 0; q < 4; ++q) {
      float acc = 0.f;
#pragma unroll
      for (int k = 0; k < 8; ++k) acc += gr[k] * w[q][k];
      s[q] += acc;
      ss[q] += acc * acc;
    }
  }
#pragma unroll
  for (int q = 0; q < 4; ++q) {
    atomicAdd(&sA1[c + q], s[q]);
    atomicAdd(&qA1[c + q], ss[q]);
  }
}

// ---------------- k1c: raw Y1, BN1+ReLU, split, write TILED-SWIZZLED ----------------
__global__ __launch_bounds__(256) void k1c(
    const float* __restrict__ G, const float* __restrict__ W1,
    const float* __restrict__ sA1, const float* __restrict__ qA1,
    const float* __restrict__ g1, const float* __restrict__ be1,
    ushort* __restrict__ X1thi, ushort* __restrict__ X1tlo) {
  int r0 = blockIdx.x * 8;
  int c = threadIdx.x * 4;
  float w[4][8];
#pragma unroll
  for (int q = 0; q < 4; ++q)
#pragma unroll
    for (int k = 0; k < 8; ++k) w[q][k] = W1[(c + q) * 8 + k];
  float sc[4], sh[4];
#pragma unroll
  for (int q = 0; q < 4; ++q)
    bn_coef(sA1[c + q], qA1[c + q], g1[c + q], be1[c + q], sc[q], sh[q]);
  int kt = c >> 6, chunk = (c >> 3) & 7, e = c & 7;
  for (int r = 0; r < 8; ++r) {
    int b = r0 + r;
    const float4 g0 = *(const float4*)&G[(size_t)b * 8];
    const float4 g1v = *(const float4*)&G[(size_t)b * 8 + 4];
    float gr[8] = {g0.x, g0.y, g0.z, g0.w, g1v.x, g1v.y, g1v.z, g1v.w};
    short hs[4], ls[4];
#pragma unroll
    for (int q = 0; q < 4; ++q) {
      float acc = 0.f;
#pragma unroll
      for (int k = 0; k < 8; ++k) acc += gr[k] * w[q][k];
      float x = fmaxf(0.f, acc * sc[q] + sh[q]);
      split2(x, hs[q], ls[q]);
    }
    int mt = b >> 7, rr = b & 127;
    size_t o = ((size_t)(mt * 16 + kt) << 13) + rr * 64 + ((chunk ^ (rr & 7)) << 3) + e;
    *(ushort4*)&X1thi[o] = make_ushort4((ushort)hs[0], (ushort)hs[1],
                                        (ushort)hs[2], (ushort)hs[3]);
    *(ushort4*)&X1tlo[o] = make_ushort4((ushort)ls[0], (ushort)ls[1],
                                        (ushort)ls[2], (ushort)ls[3]);
  }
}

// ---------------- k2: MFMA GEMM2 (3-term), gload_lds staging, fused stats ----------------
__global__ __launch_bounds__(512) void k2_mfma(
    const ushort* __restrict__ X1thi, const ushort* __restrict__ X1tlo,
    const ushort* __restrict__ W2thi, const ushort* __restrict__ W2tlo,
    float* __restrict__ Y2, float* __restrict__ sA2, float* __restrict__ qA2) {
  __shared__ short lAhi[128 * 64], lAlo[128 * 64];
  __shared__ short lBhi[64 * 64], lBlo[64 * 64];
  int id = blockIdx.x;
  int xcd = id & 7, slot = id >> 3;
  int g = slot >> 4, wi = slot & 15;
  int bx = (xcd & 3) * 4 + (wi & 3);
  int by = ((xcd >> 2) * 2 + g) * 4 + (wi >> 2);
  int b0 = bx * 128, j0 = by * 64;
  int tid = threadIdx.x;
  int lane = tid & 63, wave = tid >> 6;
  int wm = wave >> 1, wn = wave & 1;
  int woff = wave * 1024 + lane * 16;
  int loff = wave * 1024;
  f32x4 acc[2][2] = {};
  for (int kt = 0; kt < 16; ++kt) {
    const char* ga = (const char*)(X1thi + ((size_t)(bx * 16 + kt) << 13));
    const char* gl = (const char*)(X1tlo + ((size_t)(bx * 16 + kt) << 13));
    const char* gb = (const char*)(W2thi + ((size_t)(by * 16 + kt) << 12));
    const char* gc = (const char*)(W2tlo + ((size_t)(by * 16 + kt) << 12));
    gload16(ga + woff, (char*)lAhi + loff);
    gload16(ga + woff + 8192, (char*)lAhi + loff + 8192);
    gload16(gl + woff, (char*)lAlo + loff);
    gload16(gl + woff + 8192, (char*)lAlo + loff + 8192);
    gload16(gb + woff, (char*)lBhi + loff);
    gload16(gc + woff, (char*)lBlo + loff);
    __syncthreads();
#pragma unroll
    for (int kk = 0; kk < 2; ++kk) {
      int ch = kk * 4 + (lane >> 4);
      bf16x8 ah[2], al[2], bh[2], bl[2];
#pragma unroll
      for (int mi = 0; mi < 2; ++mi) {
        int rr = wm * 32 + mi * 16 + (lane & 15);
        int ad = rr * 64 + ((ch ^ (rr & 7)) << 3);
        ah[mi] = *(const bf16x8*)&lAhi[ad];
        al[mi] = *(const bf16x8*)&lAlo[ad];
      }
#pragma unroll
      for (int ni = 0; ni < 2; ++ni) {
        int rr = wn * 32 + ni * 16 + (lane & 15);
        int bd = rr * 64 + ((ch ^ (rr & 7)) << 3);
        bh[ni] = *(const bf16x8*)&lBhi[bd];
        bl[ni] = *(const bf16x8*)&lBlo[bd];
      }
#pragma unroll
      for (int mi = 0; mi < 2; ++mi)
#pragma unroll
        for (int ni = 0; ni < 2; ++ni) {
          acc[mi][ni] = __builtin_amdgcn_mfma_f32_16x16x32_bf16(
              ah[mi], bh[ni], acc[mi][ni], 0, 0, 0);
          acc[mi][ni] = __builtin_amdgcn_mfma_f32_16x16x32_bf16(
              al[mi], bh[ni], acc[mi][ni], 0, 0, 0);
          acc[mi][ni] = __builtin_amdgcn_mfma_f32_16x16x32_bf16(
              ah[mi], bl[ni], acc[mi][ni], 0, 0, 0);
        }
    }
    __syncthreads();
  }
#pragma unroll
  for (int mi = 0; mi < 2; ++mi)
#pragma unroll
    for (int ni = 0; ni < 2; ++ni) {
      int col = j0 + wn * 32 + ni * 16 + (lane & 15);
#pragma unroll
      for (int r = 0; r < 4; ++r) {
        int row = b0 + wm * 32 + mi * 16 + (lane >> 4) * 4 + r;
        Y2[(size_t)row * 1024 + col] = acc[mi][ni][r];
      }
    }
#pragma unroll
  for (int ni = 0; ni < 2; ++ni) {
    float s = 0.f, q = 0.f;
#pragma unroll
    for (int mi = 0; mi < 2; ++mi)
#pragma unroll
      for (int r = 0; r < 4; ++r) {
        float v = acc[mi][ni][r];
        s += v;
        q += v * v;
      }
    s += __shfl_xor(s, 16);
    q += __shfl_xor(q, 16);
    s += __shfl_xor(s, 32);
    q += __shfl_xor(q, 32);
    if ((lane >> 4) == 0) {
      int col = j0 + wn * 32 + ni * 16 + lane;
      atomicAdd(&sA2[col], s);
      atomicAdd(&qA2[col], q);
    }
  }
}

// ---------------- k4: MFMA GEMM3, inline BN2 coefs + ReLU, atomic into Y3 ----------------
__global__ __launch_bounds__(256) void k4_mfma(
    const float* __restrict__ Y2, const float* __restrict__ sA2,
    const float* __restrict__ qA2, const float* __restrict__ g2,
    const float* __restrict__ be2, const ushort* __restrict__ W3hi,
    const ushort* __restrict__ W3lo, float* __restrict__ Y3) {
  __shared__ short lAhi[32 * 64], lAlo[32 * 64];
  int b0 = blockIdx.x * 32;
  int kb = blockIdx.y * 128;
  int tid = threadIdx.x;
  int lane = tid & 63, wave = tid >> 6;
  int wm = wave & 1, wn = wave >> 1;
  f32x4 acc[5] = {};
  int srow = tid >> 3, sch = tid & 7;
  for (int k0 = 0; k0 < 128; k0 += 64) {
    int kg = kb + k0 + sch * 8;
    const float* src = &Y2[(size_t)(b0 + srow) * 1024 + kg];
    float4 f0 = *(const float4*)src;
    float4 f1 = *(const float4*)(src + 4);
    float4 sv0 = *(const float4*)&sA2[kg];
    float4 sv1 = *(const float4*)&sA2[kg + 4];
    float4 qv0 = *(const float4*)&qA2[kg];
    float4 qv1 = *(const float4*)&qA2[kg + 4];
    float4 gv0 = *(const float4*)&g2[kg];
    float4 gv1 = *(const float4*)&g2[kg + 4];
    float4 bv0 = *(const float4*)&be2[kg];
    float4 bv1 = *(const float4*)&be2[kg + 4];
    float e[8] = {f0.x, f0.y, f0.z, f0.w, f1.x, f1.y, f1.z, f1.w};
    float sv[8] = {sv0.x, sv0.y, sv0.z, sv0.w, sv1.x, sv1.y, sv1.z, sv1.w};
    float qv[8] = {qv0.x, qv0.y, qv0.z, qv0.w, qv1.x, qv1.y, qv1.z, qv1.w};
    float gv[8] = {gv0.x, gv0.y, gv0.z, gv0.w, gv1.x, gv1.y, gv1.z, gv1.w};
    float bev[8] = {bv0.x, bv0.y, bv0.z, bv0.w, bv1.x, bv1.y, bv1.z, bv1.w};
    bf16x8 hh, ll;
#pragma unroll
    for (int q = 0; q < 8; ++q) {
      float sc, sh;
      bn_coef(sv[q], qv[q], gv[q], bev[q], sc, sh);
      float x = fmaxf(0.f, fmaf(e[q], sc, sh));
      short h, l;
      split2(x, h, l);
      hh[q] = h;
      ll[q] = l;
    }
    if (k0) __syncthreads();
    int d = srow * 64 + ((sch ^ (srow & 7)) << 3);
    *(bf16x8*)&lAhi[d] = hh;
    *(bf16x8*)&lAlo[d] = ll;
    __syncthreads();
#pragma unroll
    for (int kk = 0; kk < 2; ++kk) {
      int r = wm * 16 + (lane & 15);
      int ch = kk * 4 + (lane >> 4);
      int ad = r * 64 + ((ch ^ (r & 7)) << 3);
      bf16x8 ah = *(const bf16x8*)&lAhi[ad];
      bf16x8 al = *(const bf16x8*)&lAlo[ad];
#pragma unroll
      for (int ni = 0; ni < 5; ++ni) {
        int col = wn * 80 + ni * 16 + (lane & 15);
        size_t wo = (size_t)col * 1024 + kb + k0 + kk * 32 + (lane >> 4) * 8;
        bf16x8 bh = *(const bf16x8*)&W3hi[wo];
        bf16x8 bl = *(const bf16x8*)&W3lo[wo];
        acc[ni] = __builtin_amdgcn_mfma_f32_16x16x32_bf16(ah, bh, acc[ni], 0, 0, 0);
        acc[ni] = __builtin_amdgcn_mfma_f32_16x16x32_bf16(al, bh, acc[ni], 0, 0, 0);
        acc[ni] = __builtin_amdgcn_mfma_f32_16x16x32_bf16(ah, bl, acc[ni], 0, 0, 0);
      }
    }
  }
#pragma unroll
  for (int ni = 0; ni < 5; ++ni) {
    int col = wn * 80 + ni * 16 + (lane & 15);
    if (col < 150) {
#pragma unroll
      for (int r = 0; r < 4; ++r) {
        int row = b0 + wm * 16 + (lane >> 4) * 4 + r;
        atomicAdd(&Y3[(size_t)row * 150 + col], acc[ni][r]);
      }
    }
  }
}

// ---------------- k5s: raw Y3 column stats -> atomic accumulators ----------------
__global__ __launch_bounds__(256) void k5s(const float* __restrict__ Y3,
                                           float* __restrict__ sA3,
                                           float* __restrict__ qA3) {
  int r0 = blockIdx.x * 8;
  int j = threadIdx.x;
  if (j >= 150) return;
  float s = 0.f, q = 0.f;
  for (int r = 0; r < 8; ++r) {
    float v = Y3[(size_t)(r0 + r) * 150 + j];
    s += v;
    q += v * v;
  }
  atomicAdd(&sA3[j], s);
  atomicAdd(&qA3[j], q);
}

// ---------------- k6a: BN3+ReLU + ct1 + composite conv -> lorentz rational coefs ----------------
// Spre per (r,cc): q0={c1,c2,A,B}, q1={nC,0,0,0}
//   D(x)=x^2+c1*x+c2 ; t1=A-B*x (=n^2*D) ; t2=B*x+nC (=kap2*D)
__global__ __launch_bounds__(256) void k6a(
    const float* __restrict__ Y3, const float* __restrict__ sA3,
    const float* __restrict__ qA3, const float* __restrict__ g3,
    const float* __restrict__ be3, const float* __restrict__ ct1_w,
    const float* __restrict__ ct1_b, const float* __restrict__ ct2_w,
    const float* __restrict__ ct2_b, const float* __restrict__ ct3_w,
    const float* __restrict__ ct3_b, const float* __restrict__ cf_w,
    const float* __restrict__ cf_b, float* __restrict__ Spre) {
  __shared__ float wt1[32], wb1[4], wt2L[80], wb2L[4], w3fL[20];
  __shared__ float Cc[36], cfb2C[1], cfbraw[1];
  __shared__ float h0p[4][160];
  __shared__ float hA[4][4][312];
  __shared__ float Srow[4][304];
  int tid = threadIdx.x;
  if (tid < 32) wt1[tid] = ct1_w[tid];
  else if (tid < 36) wb1[tid - 32] = ct1_b[tid - 32];
  else if (tid < 116) wt2L[tid - 36] = ct2_w[tid - 36];
  else if (tid < 120) wb2L[tid - 116] = ct2_b[tid - 116];
  else if (tid < 140) {
    int i = (tid - 120) / 5, j = (tid - 120) % 5;
    float s = 0.f;
#pragma unroll
    for (int p = 0; p < 4; ++p) s += cf_w[p] * ct3_w[(i * 4 + p) * 5 + j];
    w3fL[tid - 120] = s;
  } else if (tid == 140) {
    float s = cf_b[0];
#pragma unroll
    for (int p = 0; p < 4; ++p) s += cf_w[p] * ct3_b[p];
    cfbraw[0] = s;
  }
  int w = tid >> 6;
  int lane = tid & 63;
  int r = blockIdx.x * 4 + w;
  for (int i = lane; i < 160; i += 64) {
    int k = i - 2;
    float v = 0.f;
    if (k >= 0 && k < 150) {
      float sc, sh;
      bn_coef(sA3[k], qA3[k], g3[k], be3[k], sc, sh);
      v = fmaxf(0.f, Y3[(size_t)r * 150 + k] * sc + sh);
    }
    h0p[w][i] = v;
  }
  if (lane < 12) {
    int z = (lane < 4) ? lane : (300 + lane);
#pragma unroll
    for (int o = 0; o < 4; ++o) hA[w][o][z] = 0.f;
  }
  __syncthreads();
  if (tid < 36) {
    int i = tid / 9, u = tid % 9;
    float s = 0.f;
#pragma unroll
    for (int o = 0; o < 4; ++o) {
      int j2lo = (u > 4) ? (u - 4) : 0;
      int j2hi = (u < 4) ? u : 4;
      for (int j2 = j2lo; j2 <= j2hi; ++j2)
        s += wt2L[(i * 4 + o) * 5 + (u - j2)] * w3fL[o * 5 + j2];
    }
    Cc[tid] = s;
  } else if (tid == 36) {
    float s = cfbraw[0];
#pragma unroll
    for (int o = 0; o < 4; ++o) {
      float t = 0.f;
#pragma unroll
      for (int j2 = 0; j2 < 5; ++j2) t += w3fL[o * 5 + j2];
      s += wb2L[o] * t;
    }
    cfb2C[0] = s;
  }
  __syncthreads();
  for (int t = lane; t < 300; t += 64) {
    int p1 = (t + 3) & 1;
    int base = (t + 3 - p1) >> 1;
    float x0 = h0p[w][2 + base];
    float x1 = h0p[w][1 + base];
    float x2 = h0p[w][base];
    float x3 = h0p[w][base - 1];
#pragma unroll
    for (int o = 0; o < 4; ++o) {
      float acc = wb1[o];
      acc += wt1[o * 8 + p1] * x0;
      acc += wt1[o * 8 + p1 + 2] * x1;
      acc += wt1[o * 8 + p1 + 4] * x2;
      acc += wt1[o * 8 + p1 + 6] * x3;
      hA[w][o][4 + t] = acc;
    }
  }
  __syncthreads();
  for (int t = lane; t < 300; t += 64) {
    float acc = cfb2C[0];
#pragma unroll
    for (int i = 0; i < 4; ++i)
#pragma unroll
      for (int u = 0; u < 9; ++u) acc += Cc[i * 9 + u] * hA[w][i][t + 8 - u];
    if (t < 2) {
      for (int j2 = t + 3; j2 <= 4; ++j2) {
        int tp_ = t + 2 - j2;
        float corr = 0.f;
        for (int o = 0; o < 4; ++o) {
          float hb = wb2L[o];
          for (int i2 = 0; i2 < 4; ++i2)
            for (int j1 = 0; j1 < 5; ++j1)
              hb += wt2L[(i2 * 4 + o) * 5 + j1] * hA[w][i2][6 + tp_ - j1];
          corr += w3fL[o * 5 + j2] * hb;
        }
        acc -= corr;
      }
    }
    if (t > 297) {
      for (int j2 = 0; j2 <= t - 298; ++j2) {
        int tp_ = t + 2 - j2;
        float corr = 0.f;
        for (int o = 0; o < 4; ++o) {
          float hb = wb2L[o];
          for (int i2 = 0; i2 < 4; ++i2)
            for (int j1 = 0; j1 < 5; ++j1)
              hb += wt2L[(i2 * 4 + o) * 5 + j1] * hA[w][i2][6 + tp_ - j1];
          corr += w3fL[o * 5 + j2] * hb;
        }
        acc -= corr;
      }
    }
    Srow[w][t] = acc;
  }
  __syncthreads();
  for (int cc = lane; cc < 100; cc += 64) {
    float s0 = Srow[w][3 * cc], s1 = Srow[w][3 * cc + 1], s2 = Srow[w][3 * cc + 2];
    float P = s0 * s0, s1s = s1 * s1, s2s = s2 * s2;
    float halfP = 0.5f * P;
    float4 q0, q1;
    q0.x = s2s - 2.f * s1s;       // c1
    q0.y = s1s * s1s;             // c2
    q0.z = halfP * (P + s1s);     // A
    q0.w = halfP;                 // B
    q1.x = halfP * (P - s1s);     // nC
    q1.y = 0.f;
    q1.z = 0.f;
    q1.w = 0.f;
    size_t o = ((size_t)r * 100 + cc) * 8;
    *(float4*)&Spre[o] = q0;
    *(float4*)&Spre[o + 4] = q1;
  }
}

// ---------------- k6b: lorentz, cc-split x4, single-rcp form ----------------
// dT = 4R/(t1c + 2R + D + t2c), R = sqrt(t1c*D)  (D>0; clamps honored)
__global__ __launch_bounds__(320) void k6b(const float* __restrict__ Spre,
                                           float* __restrict__ out) {
  int b = blockIdx.x;
  int l = threadIdx.x;
  float wl = 0.8f + (float)l * (1.0f / 300.0f);
  float x = wl * wl;
  float xn = -x;
  float acc = 0.f;
  const float4* pp = (const float4*)(Spre + (size_t)b * 800) + blockIdx.y * 50;
#pragma unroll 5
  for (int cc = 0; cc < 25; ++cc) {
    float4 q0 = pp[2 * cc];      // {c1, c2, A, B}  (uniform addr -> s_load)
    float4 q1 = pp[2 * cc + 1];  // {nC, -, -, -}
    float D = fmaf(x, x + q0.x, q0.y);
    float t1 = fmaxf(fmaf(q0.w, xn, q0.z), 0.f);
    float t2 = fmaxf(fmaf(q0.w, x, q1.x), 0.f);
    float R = __builtin_amdgcn_sqrtf(t1 * D);
    float sum = (t1 + D) + fmaf(2.f, R, t2);
    acc = fmaf(R, __builtin_amdgcn_rcpf(sum), acc);
  }
  if (l < 300) atomicAdd(&out[(size_t)b * 300 + l], 4.0f * acc);
}

extern "C" void kernel_launch(void* const* d_in, const int* in_sizes, int n_in,
                              void* d_out, int out_size, void* d_ws,
                              size_t ws_size, hipStream_t stream) {
  const float* G = (const float*)d_in[0];
  const float* w1 = (const float*)d_in[1];
  const float* g1 = (const float*)d_in[3];
  const float* be1 = (const float*)d_in[4];
  const float* w2 = (const float*)d_in[5];
  const float* g2 = (const float*)d_in[7];
  const float* be2 = (const float*)d_in[8];
  const float* w3 = (const float*)d_in[9];
  const float* g3 = (const float*)d_in[11];
  const float* be3 = (const float*)d_in[12];
  const float* ct1_w = (const float*)d_in[13];
  const float* ct1_b = (const float*)d_in[14];
  const float* ct2_w = (const float*)d_in[15];
  const float* ct2_b = (const float*)d_in[16];
  const float* ct3_w = (const float*)d_in[17];
  const float* ct3_b = (const float*)d_in[18];
  const float* cf_w = (const float*)d_in[19];
  const float* cf_b = (const float*)d_in[20];
  float* out = (float*)d_out;

  float* ws = (float*)d_ws;
  // float-offset layout:
  float* Y2 = ws;                           // [0, 2097152) k2->k4
  float* Spre = ws;                         // same region, after k4 (k6a->k6b, 1638400 f)
  ushort* X1thi = (ushort*)(ws + 2097152);  // [2097152, 3145728) k1c->k2
  ushort* X1tlo = (ushort*)(ws + 3145728);  // [3145728, 4194304) k1c->k2
  float* sA1 = ws + 4194304;                // stats block (4448 floats)
  float* qA1 = sA1 + 1024;
  float* sA2 = sA1 + 2048;
  float* qA2 = sA1 + 3072;
  float* sA3 = sA1 + 4096;
  float* qA3 = sA1 + 4288;
  ushort* W2thi = (ushort*)(ws + 4198752);  // [4198752, 4723040)
  ushort* W2tlo = (ushort*)(ws + 4723040);  // [4723040, 5247328)
  ushort* W3hi = (ushort*)(ws + 5247328);   // [5247328, 5329248)
  ushort* W3lo = (ushort*)(ws + 5329248);   // [5329248, 5411168)
  float* Y3 = ws + 5411168;                 // [5411168, 5718368)

  kpre<<<2089, 256, 0, stream>>>(w2, w3, W2thi, W2tlo, W3hi, W3lo,
                                 (float4*)sA1, (float4*)Y3, (float4*)out);
  k1s<<<256, 256, 0, stream>>>(G, w1, sA1, qA1);
  k1c<<<256, 256, 0, stream>>>(G, w1, sA1, qA1, g1, be1, X1thi, X1tlo);
  k2_mfma<<<256, 512, 0, stream>>>(X1thi, X1tlo, W2thi, W2tlo, Y2, sA2, qA2);
  k4_mfma<<<dim3(64, 8), 256, 0, stream>>>(Y2, sA2, qA2, g2, be2, W3hi, W3lo, Y3);
  k5s<<<256, 256, 0, stream>>>(Y3, sA3, qA3);
  k6a<<<512, 256, 0, stream>>>(Y3, sA3, qA3, g3, be3, ct1_w, ct1_b, ct2_w,
                               ct2_b, ct3_w, ct3_b, cf_w, cf_b, Spre);
  k6b<<<dim3(2048, 4), 320, 0, stream>>>(Spre, out);
}

// Round 19
// 116.089 us; speedup vs baseline: 1.3104x; 1.2026x over previous
//
#include <hip/hip_runtime.h>
#include <hip/hip_bf16.h>

#define EPS 1e-5f

typedef __attribute__((ext_vector_type(8))) short bf16x8;
typedef __attribute__((ext_vector_type(4))) float f32x4;

__device__ __forceinline__ void gload16(const void* g, void* l) {
  __builtin_amdgcn_global_load_lds(
      (const __attribute__((address_space(1))) unsigned int*)g,
      (__attribute__((address_space(3))) unsigned int*)l, 16, 0, 0);
}

// truncation-based hi/lo bf16 split
__device__ __forceinline__ void split2(float x, short& h, short& l) {
  unsigned u = __float_as_uint(x);
  h = (short)(u >> 16);
  float hf = __uint_as_float(u & 0xFFFF0000u);
  l = (short)(__float_as_uint(x - hf) >> 16);
}
__device__ __forceinline__ void bn_coef(float s, float q, float g, float be,
                                        float& sc, float& sh) {
  float mu = s * (1.f / 2048.f);
  float var = q * (1.f / 2048.f) - mu * mu;
  sc = g * rsqrtf(var + EPS);
  sh = be - mu * sc;
}

// ---------------- kpre: weight prep only (no zeroing needed anywhere) ----------------
// grid 1184: [0,1024) W2 hi/lo trunc-split tiled-swizzled | [1024,1184) W3 split
__global__ __launch_bounds__(256) void kpre(
    const float* __restrict__ W2, const float* __restrict__ W3,
    ushort* __restrict__ W2thi, ushort* __restrict__ W2tlo,
    ushort* __restrict__ W3hi, ushort* __restrict__ W3lo) {
  int b = blockIdx.x;
  int tid = threadIdx.x;
  if (b < 1024) {
    int c = tid * 4;
    int nt = b >> 6, rr = b & 63;
    int kt = c >> 6, chunk = (c >> 3) & 7, e = c & 7;
    float4 v = *(const float4*)&W2[(size_t)b * 1024 + c];
    float ev[4] = {v.x, v.y, v.z, v.w};
    short hh[4], ll[4];
#pragma unroll
    for (int q = 0; q < 4; ++q) split2(ev[q], hh[q], ll[q]);
    size_t o = ((size_t)(nt * 16 + kt) << 12) + rr * 64 + ((chunk ^ (rr & 7)) << 3) + e;
    *(ushort4*)&W2thi[o] = make_ushort4((ushort)hh[0], (ushort)hh[1],
                                        (ushort)hh[2], (ushort)hh[3]);
    *(ushort4*)&W2tlo[o] = make_ushort4((ushort)ll[0], (ushort)ll[1],
                                        (ushort)ll[2], (ushort)ll[3]);
  } else {
    int n = b - 1024;
    int c = tid * 4;
    float4 v = make_float4(0.f, 0.f, 0.f, 0.f);
    if (n < 150) v = *(const float4*)&W3[(size_t)n * 1024 + c];
    float e[4] = {v.x, v.y, v.z, v.w};
    short hh[4], ll[4];
#pragma unroll
    for (int q = 0; q < 4; ++q) split2(e[q], hh[q], ll[q]);
    *(ushort4*)&W3hi[(size_t)n * 1024 + c] =
        make_ushort4((ushort)hh[0], (ushort)hh[1], (ushort)hh[2], (ushort)hh[3]);
    *(ushort4*)&W3lo[(size_t)n * 1024 + c] =
        make_ushort4((ushort)ll[0], (ushort)ll[1], (ushort)ll[2], (ushort)ll[3]);
  }
}

// ---------------- k1s: deterministic layer1 stats (block owns 4 cols, tree reduce) ----------------
__global__ __launch_bounds__(256) void k1s(const float* __restrict__ G,
                                           const float* __restrict__ W1,
                                           float* __restrict__ sA1,
                                           float* __restrict__ qA1) {
  __shared__ float rs[4][256], rq[4][256];
  int c0 = blockIdx.x * 4;
  int tid = threadIdx.x;
  float w[4][8];
#pragma unroll
  for (int q = 0; q < 4; ++q)
#pragma unroll
    for (int k = 0; k < 8; ++k) w[q][k] = W1[(c0 + q) * 8 + k];
  float s[4] = {}, ss[4] = {};
  for (int i = 0; i < 8; ++i) {
    int r = tid * 8 + i;
    const float4 g0 = *(const float4*)&G[(size_t)r * 8];
    const float4 g1 = *(const float4*)&G[(size_t)r * 8 + 4];
    float gr[8] = {g0.x, g0.y, g0.z, g0.w, g1.x, g1.y, g1.z, g1.w};
#pragma unroll
    for (int q = 0; q < 4; ++q) {
      float acc = 0.f;
#pragma unroll
      for (int k = 0; k < 8; ++k) acc += gr[k] * w[q][k];
      s[q] += acc;
      ss[q] += acc * acc;
    }
  }
#pragma unroll
  for (int q = 0; q < 4; ++q) {
    rs[q][tid] = s[q];
    rq[q][tid] = ss[q];
  }
  __syncthreads();
  for (int off = 128; off > 0; off >>= 1) {
    if (tid < off) {
#pragma unroll
      for (int q = 0; q < 4; ++q) {
        rs[q][tid] += rs[q][tid + off];
        rq[q][tid] += rq[q][tid + off];
      }
    }
    __syncthreads();
  }
  if (tid < 4) {
    sA1[c0 + tid] = rs[tid][0];
    qA1[c0 + tid] = rq[tid][0];
  }
}

// ---------------- k1c: raw Y1, BN1+ReLU, split, write TILED-SWIZZLED ----------------
__global__ __launch_bounds__(256) void k1c(
    const float* __restrict__ G, const float* __restrict__ W1,
    const float* __restrict__ sA1, const float* __restrict__ qA1,
    const float* __restrict__ g1, const float* __restrict__ be1,
    ushort* __restrict__ X1thi, ushort* __restrict__ X1tlo) {
  int r0 = blockIdx.x * 8;
  int c = threadIdx.x * 4;
  float w[4][8];
#pragma unroll
  for (int q = 0; q < 4; ++q)
#pragma unroll
    for (int k = 0; k < 8; ++k) w[q][k] = W1[(c + q) * 8 + k];
  float sc[4], sh[4];
#pragma unroll
  for (int q = 0; q < 4; ++q)
    bn_coef(sA1[c + q], qA1[c + q], g1[c + q], be1[c + q], sc[q], sh[q]);
  int kt = c >> 6, chunk = (c >> 3) & 7, e = c & 7;
  for (int r = 0; r < 8; ++r) {
    int b = r0 + r;
    const float4 g0 = *(const float4*)&G[(size_t)b * 8];
    const float4 g1v = *(const float4*)&G[(size_t)b * 8 + 4];
    float gr[8] = {g0.x, g0.y, g0.z, g0.w, g1v.x, g1v.y, g1v.z, g1v.w};
    short hs[4], ls[4];
#pragma unroll
    for (int q = 0; q < 4; ++q) {
      float acc = 0.f;
#pragma unroll
      for (int k = 0; k < 8; ++k) acc += gr[k] * w[q][k];
      float x = fmaxf(0.f, acc * sc[q] + sh[q]);
      split2(x, hs[q], ls[q]);
    }
    int mt = b >> 7, rr = b & 127;
    size_t o = ((size_t)(mt * 16 + kt) << 13) + rr * 64 + ((chunk ^ (rr & 7)) << 3) + e;
    *(ushort4*)&X1thi[o] = make_ushort4((ushort)hs[0], (ushort)hs[1],
                                        (ushort)hs[2], (ushort)hs[3]);
    *(ushort4*)&X1tlo[o] = make_ushort4((ushort)ls[0], (ushort)ls[1],
                                        (ushort)ls[2], (ushort)ls[3]);
  }
}

// ---------------- k2: MFMA GEMM2 (3-term), gload_lds staging, partial stats stores ----------------
__global__ __launch_bounds__(512) void k2_mfma(
    const ushort* __restrict__ X1thi, const ushort* __restrict__ X1tlo,
    const ushort* __restrict__ W2thi, const ushort* __restrict__ W2tlo,
    float* __restrict__ Y2, float* __restrict__ s2p, float* __restrict__ q2p) {
  __shared__ short lAhi[128 * 64], lAlo[128 * 64];
  __shared__ short lBhi[64 * 64], lBlo[64 * 64];
  int id = blockIdx.x;
  int xcd = id & 7, slot = id >> 3;
  int g = slot >> 4, wi = slot & 15;
  int bx = (xcd & 3) * 4 + (wi & 3);
  int by = ((xcd >> 2) * 2 + g) * 4 + (wi >> 2);
  int b0 = bx * 128, j0 = by * 64;
  int tid = threadIdx.x;
  int lane = tid & 63, wave = tid >> 6;
  int wm = wave >> 1, wn = wave & 1;
  int woff = wave * 1024 + lane * 16;
  int loff = wave * 1024;
  f32x4 acc[2][2] = {};
  for (int kt = 0; kt < 16; ++kt) {
    const char* ga = (const char*)(X1thi + ((size_t)(bx * 16 + kt) << 13));
    const char* gl = (const char*)(X1tlo + ((size_t)(bx * 16 + kt) << 13));
    const char* gb = (const char*)(W2thi + ((size_t)(by * 16 + kt) << 12));
    const char* gc = (const char*)(W2tlo + ((size_t)(by * 16 + kt) << 12));
    gload16(ga + woff, (char*)lAhi + loff);
    gload16(ga + woff + 8192, (char*)lAhi + loff + 8192);
    gload16(gl + woff, (char*)lAlo + loff);
    gload16(gl + woff + 8192, (char*)lAlo + loff + 8192);
    gload16(gb + woff, (char*)lBhi + loff);
    gload16(gc + woff, (char*)lBlo + loff);
    __syncthreads();
#pragma unroll
    for (int kk = 0; kk < 2; ++kk) {
      int ch = kk * 4 + (lane >> 4);
      bf16x8 ah[2], al[2], bh[2], bl[2];
#pragma unroll
      for (int mi = 0; mi < 2; ++mi) {
        int rr = wm * 32 + mi * 16 + (lane & 15);
        int ad = rr * 64 + ((ch ^ (rr & 7)) << 3);
        ah[mi] = *(const bf16x8*)&lAhi[ad];
        al[mi] = *(const bf16x8*)&lAlo[ad];
      }
#pragma unroll
      for (int ni = 0; ni < 2; ++ni) {
        int rr = wn * 32 + ni * 16 + (lane & 15);
        int bd = rr * 64 + ((ch ^ (rr & 7)) << 3);
        bh[ni] = *(const bf16x8*)&lBhi[bd];
        bl[ni] = *(const bf16x8*)&lBlo[bd];
      }
#pragma unroll
      for (int mi = 0; mi < 2; ++mi)
#pragma unroll
        for (int ni = 0; ni < 2; ++ni) {
          acc[mi][ni] = __builtin_amdgcn_mfma_f32_16x16x32_bf16(
              ah[mi], bh[ni], acc[mi][ni], 0, 0, 0);
          acc[mi][ni] = __builtin_amdgcn_mfma_f32_16x16x32_bf16(
              al[mi], bh[ni], acc[mi][ni], 0, 0, 0);
          acc[mi][ni] = __builtin_amdgcn_mfma_f32_16x16x32_bf16(
              ah[mi], bl[ni], acc[mi][ni], 0, 0, 0);
        }
    }
    __syncthreads();
  }
#pragma unroll
  for (int mi = 0; mi < 2; ++mi)
#pragma unroll
    for (int ni = 0; ni < 2; ++ni) {
      int col = j0 + wn * 32 + ni * 16 + (lane & 15);
#pragma unroll
      for (int r = 0; r < 4; ++r) {
        int row = b0 + wm * 32 + mi * 16 + (lane >> 4) * 4 + r;
        Y2[(size_t)row * 1024 + col] = acc[mi][ni][r];
      }
    }
  // deterministic per-(bx,wm) partial stats: plain stores, unique writers
#pragma unroll
  for (int ni = 0; ni < 2; ++ni) {
    float s = 0.f, q = 0.f;
#pragma unroll
    for (int mi = 0; mi < 2; ++mi)
#pragma unroll
      for (int r = 0; r < 4; ++r) {
        float v = acc[mi][ni][r];
        s += v;
        q += v * v;
      }
    s += __shfl_xor(s, 16);
    q += __shfl_xor(q, 16);
    s += __shfl_xor(s, 32);
    q += __shfl_xor(q, 32);
    if ((lane >> 4) == 0) {
      int col = j0 + wn * 32 + ni * 16 + lane;
      int p = bx * 4 + wm;
      s2p[p * 1024 + col] = s;
      q2p[p * 1024 + col] = q;
    }
  }
}

// ---------------- kc2: reduce 64 partials/col (shfl tree) -> BN2 coefs ----------------
__global__ __launch_bounds__(64) void kc2(const float* __restrict__ s2p,
                                          const float* __restrict__ q2p,
                                          const float* __restrict__ g2,
                                          const float* __restrict__ be2,
                                          float* __restrict__ scale2,
                                          float* __restrict__ shift2) {
  int j = blockIdx.x;
  int t = threadIdx.x;
  float s = s2p[t * 1024 + j];
  float q = q2p[t * 1024 + j];
#pragma unroll
  for (int off = 32; off > 0; off >>= 1) {
    s += __shfl_xor(s, off);
    q += __shfl_xor(q, off);
  }
  if (t == 0) {
    float sc, sh;
    bn_coef(s, q, g2[j], be2[j], sc, sh);
    scale2[j] = sc;
    shift2[j] = sh;
  }
}

// ---------------- k4: MFMA GEMM3, BN2+ReLU on A, split-K partials (plain store) ----------------
__global__ __launch_bounds__(256) void k4_mfma(
    const float* __restrict__ Y2, const float* __restrict__ scale2,
    const float* __restrict__ shift2, const ushort* __restrict__ W3hi,
    const ushort* __restrict__ W3lo, float* __restrict__ P) {
  __shared__ short lAhi[32 * 64], lAlo[32 * 64];
  int b0 = blockIdx.x * 32;
  int kz = blockIdx.y;
  int kb = kz * 128;
  int tid = threadIdx.x;
  int lane = tid & 63, wave = tid >> 6;
  int wm = wave & 1, wn = wave >> 1;
  f32x4 acc[5] = {};
  int srow = tid >> 3, sch = tid & 7;
  for (int k0 = 0; k0 < 128; k0 += 64) {
    int kg = kb + k0 + sch * 8;
    const float* src = &Y2[(size_t)(b0 + srow) * 1024 + kg];
    float4 f0 = *(const float4*)src;
    float4 f1 = *(const float4*)(src + 4);
    float4 c0 = *(const float4*)&scale2[kg];
    float4 c1 = *(const float4*)&scale2[kg + 4];
    float4 s0 = *(const float4*)&shift2[kg];
    float4 s1 = *(const float4*)&shift2[kg + 4];
    float e[8] = {f0.x, f0.y, f0.z, f0.w, f1.x, f1.y, f1.z, f1.w};
    float cs[8] = {c0.x, c0.y, c0.z, c0.w, c1.x, c1.y, c1.z, c1.w};
    float sh[8] = {s0.x, s0.y, s0.z, s0.w, s1.x, s1.y, s1.z, s1.w};
    bf16x8 hh, ll;
#pragma unroll
    for (int q = 0; q < 8; ++q) {
      float x = fmaxf(0.f, fmaf(e[q], cs[q], sh[q]));
      short h, l;
      split2(x, h, l);
      hh[q] = h;
      ll[q] = l;
    }
    if (k0) __syncthreads();
    int d = srow * 64 + ((sch ^ (srow & 7)) << 3);
    *(bf16x8*)&lAhi[d] = hh;
    *(bf16x8*)&lAlo[d] = ll;
    __syncthreads();
#pragma unroll
    for (int kk = 0; kk < 2; ++kk) {
      int r = wm * 16 + (lane & 15);
      int ch = kk * 4 + (lane >> 4);
      int ad = r * 64 + ((ch ^ (r & 7)) << 3);
      bf16x8 ah = *(const bf16x8*)&lAhi[ad];
      bf16x8 al = *(const bf16x8*)&lAlo[ad];
#pragma unroll
      for (int ni = 0; ni < 5; ++ni) {
        int col = wn * 80 + ni * 16 + (lane & 15);
        size_t wo = (size_t)col * 1024 + kb + k0 + kk * 32 + (lane >> 4) * 8;
        bf16x8 bh = *(const bf16x8*)&W3hi[wo];
        bf16x8 bl = *(const bf16x8*)&W3lo[wo];
        acc[ni] = __builtin_amdgcn_mfma_f32_16x16x32_bf16(ah, bh, acc[ni], 0, 0, 0);
        acc[ni] = __builtin_amdgcn_mfma_f32_16x16x32_bf16(al, bh, acc[ni], 0, 0, 0);
        acc[ni] = __builtin_amdgcn_mfma_f32_16x16x32_bf16(ah, bl, acc[ni], 0, 0, 0);
      }
    }
  }
#pragma unroll
  for (int ni = 0; ni < 5; ++ni) {
    int col = wn * 80 + ni * 16 + (lane & 15);
    if (col < 150) {
#pragma unroll
      for (int r = 0; r < 4; ++r) {
        int row = b0 + wm * 16 + (lane >> 4) * 4 + r;
        P[(size_t)kz * 307200 + (size_t)row * 150 + col] = acc[ni][r];
      }
    }
  }
}

// ---------------- k5a: sum split-K partials (fixed order) -> Y3 + stat partials ----------------
__global__ __launch_bounds__(192) void k5a(const float* __restrict__ P,
                                           float* __restrict__ Y3,
                                           float* __restrict__ p3s,
                                           float* __restrict__ p3q) {
  int r0 = blockIdx.x * 8;
  int j = threadIdx.x;
  if (j >= 150) return;
  float s = 0.f, q = 0.f;
  for (int r = 0; r < 8; ++r) {
    size_t base = (size_t)(r0 + r) * 150 + j;
    float v = P[base];
#pragma unroll
    for (int kz = 1; kz < 8; ++kz) v += P[(size_t)kz * 307200 + base];
    Y3[base] = v;
    s += v;
    q += v * v;
  }
  p3s[blockIdx.x * 160 + j] = s;
  p3q[blockIdx.x * 160 + j] = q;
}

// ---------------- k5b: tree-reduce 256 stat partials per column ----------------
__global__ __launch_bounds__(256) void k5b(const float* __restrict__ p3s,
                                           const float* __restrict__ p3q,
                                           float* __restrict__ sA3,
                                           float* __restrict__ qA3) {
  __shared__ float rs[256], rq[256];
  int j = blockIdx.x;
  int t = threadIdx.x;
  rs[t] = p3s[t * 160 + j];
  rq[t] = p3q[t * 160 + j];
  __syncthreads();
  for (int off = 128; off > 0; off >>= 1) {
    if (t < off) {
      rs[t] += rs[t + off];
      rq[t] += rq[t + off];
    }
    __syncthreads();
  }
  if (t == 0) {
    sA3[j] = rs[0];
    qA3[j] = rq[0];
  }
}

// ---------------- k6a: BN3+ReLU + ct1 + composite conv -> lorentz rational coefs ----------------
__global__ __launch_bounds__(256) void k6a(
    const float* __restrict__ Y3, const float* __restrict__ sA3,
    const float* __restrict__ qA3, const float* __restrict__ g3,
    const float* __restrict__ be3, const float* __restrict__ ct1_w,
    const float* __restrict__ ct1_b, const float* __restrict__ ct2_w,
    const float* __restrict__ ct2_b, const float* __restrict__ ct3_w,
    const float* __restrict__ ct3_b, const float* __restrict__ cf_w,
    const float* __restrict__ cf_b, float* __restrict__ Spre) {
  __shared__ float wt1[32], wb1[4], wt2L[80], wb2L[4], w3fL[20];
  __shared__ float Cc[36], cfb2C[1], cfbraw[1];
  __shared__ float h0p[4][160];
  __shared__ float hA[4][4][312];
  __shared__ float Srow[4][304];
  int tid = threadIdx.x;
  if (tid < 32) wt1[tid] = ct1_w[tid];
  else if (tid < 36) wb1[tid - 32] = ct1_b[tid - 32];
  else if (tid < 116) wt2L[tid - 36] = ct2_w[tid - 36];
  else if (tid < 120) wb2L[tid - 116] = ct2_b[tid - 116];
  else if (tid < 140) {
    int i = (tid - 120) / 5, j = (tid - 120) % 5;
    float s = 0.f;
#pragma unroll
    for (int p = 0; p < 4; ++p) s += cf_w[p] * ct3_w[(i * 4 + p) * 5 + j];
    w3fL[tid - 120] = s;
  } else if (tid == 140) {
    float s = cf_b[0];
#pragma unroll
    for (int p = 0; p < 4; ++p) s += cf_w[p] * ct3_b[p];
    cfbraw[0] = s;
  }
  int w = tid >> 6;
  int lane = tid & 63;
  int r = blockIdx.x * 4 + w;
  for (int i = lane; i < 160; i += 64) {
    int k = i - 2;
    float v = 0.f;
    if (k >= 0 && k < 150) {
      float sc, sh;
      bn_coef(sA3[k], qA3[k], g3[k], be3[k], sc, sh);
      v = fmaxf(0.f, Y3[(size_t)r * 150 + k] * sc + sh);
    }
    h0p[w][i] = v;
  }
  if (lane < 12) {
    int z = (lane < 4) ? lane : (300 + lane);
#pragma unroll
    for (int o = 0; o < 4; ++o) hA[w][o][z] = 0.f;
  }
  __syncthreads();
  if (tid < 36) {
    int i = tid / 9, u = tid % 9;
    float s = 0.f;
#pragma unroll
    for (int o = 0; o < 4; ++o) {
      int j2lo = (u > 4) ? (u - 4) : 0;
      int j2hi = (u < 4) ? u : 4;
      for (int j2 = j2lo; j2 <= j2hi; ++j2)
        s += wt2L[(i * 4 + o) * 5 + (u - j2)] * w3fL[o * 5 + j2];
    }
    Cc[tid] = s;
  } else if (tid == 36) {
    float s = cfbraw[0];
#pragma unroll
    for (int o = 0; o < 4; ++o) {
      float t = 0.f;
#pragma unroll
      for (int j2 = 0; j2 < 5; ++j2) t += w3fL[o * 5 + j2];
      s += wb2L[o] * t;
    }
    cfb2C[0] = s;
  }
  __syncthreads();
  for (int t = lane; t < 300; t += 64) {
    int p1 = (t + 3) & 1;
    int base = (t + 3 - p1) >> 1;
    float x0 = h0p[w][2 + base];
    float x1 = h0p[w][1 + base];
    float x2 = h0p[w][base];
    float x3 = h0p[w][base - 1];
#pragma unroll
    for (int o = 0; o < 4; ++o) {
      float acc = wb1[o];
      acc += wt1[o * 8 + p1] * x0;
      acc += wt1[o * 8 + p1 + 2] * x1;
      acc += wt1[o * 8 + p1 + 4] * x2;
      acc += wt1[o * 8 + p1 + 6] * x3;
      hA[w][o][4 + t] = acc;
    }
  }
  __syncthreads();
  for (int t = lane; t < 300; t += 64) {
    float acc = cfb2C[0];
#pragma unroll
    for (int i = 0; i < 4; ++i)
#pragma unroll
      for (int u = 0; u < 9; ++u) acc += Cc[i * 9 + u] * hA[w][i][t + 8 - u];
    if (t < 2) {
      for (int j2 = t + 3; j2 <= 4; ++j2) {
        int tp_ = t + 2 - j2;
        float corr = 0.f;
        for (int o = 0; o < 4; ++o) {
          float hb = wb2L[o];
          for (int i2 = 0; i2 < 4; ++i2)
            for (int j1 = 0; j1 < 5; ++j1)
              hb += wt2L[(i2 * 4 + o) * 5 + j1] * hA[w][i2][6 + tp_ - j1];
          corr += w3fL[o * 5 + j2] * hb;
        }
        acc -= corr;
      }
    }
    if (t > 297) {
      for (int j2 = 0; j2 <= t - 298; ++j2) {
        int tp_ = t + 2 - j2;
        float corr = 0.f;
        for (int o = 0; o < 4; ++o) {
          float hb = wb2L[o];
          for (int i2 = 0; i2 < 4; ++i2)
            for (int j1 = 0; j1 < 5; ++j1)
              hb += wt2L[(i2 * 4 + o) * 5 + j1] * hA[w][i2][6 + tp_ - j1];
          corr += w3fL[o * 5 + j2] * hb;
        }
        acc -= corr;
      }
    }
    Srow[w][t] = acc;
  }
  __syncthreads();
  for (int cc = lane; cc < 100; cc += 64) {
    float s0 = Srow[w][3 * cc], s1 = Srow[w][3 * cc + 1], s2 = Srow[w][3 * cc + 2];
    float P = s0 * s0, s1s = s1 * s1, s2s = s2 * s2;
    float halfP = 0.5f * P;
    float4 q0, q1;
    q0.x = s2s - 2.f * s1s;
    q0.y = s1s * s1s;
    q0.z = halfP * (P + s1s);
    q0.w = halfP;
    q1.x = halfP * (P - s1s);
    q1.y = 0.f;
    q1.z = 0.f;
    q1.w = 0.f;
    size_t o = ((size_t)r * 100 + cc) * 8;
    *(float4*)&Spre[o] = q0;
    *(float4*)&Spre[o + 4] = q1;
  }
}

// ---------------- k6b: lorentz, cc-split x4, single-rcp, partial stores ----------------
__global__ __launch_bounds__(320) void k6b(const float* __restrict__ Spre,
                                           float* __restrict__ op) {
  int b = blockIdx.x;
  int y = blockIdx.y;
  int l = threadIdx.x;
  float wl = 0.8f + (float)l * (1.0f / 300.0f);
  float x = wl * wl;
  float xn = -x;
  float acc = 0.f;
  const float4* pp = (const float4*)(Spre + (size_t)b * 800) + y * 50;
#pragma unroll 5
  for (int cc = 0; cc < 25; ++cc) {
    float4 q0 = pp[2 * cc];
    float4 q1 = pp[2 * cc + 1];
    float D = fmaf(x, x + q0.x, q0.y);
    float t1 = fmaxf(fmaf(q0.w, xn, q0.z), 0.f);
    float t2 = fmaxf(fmaf(q0.w, x, q1.x), 0.f);
    float R = __builtin_amdgcn_sqrtf(t1 * D);
    float sum = (t1 + D) + fmaf(2.f, R, t2);
    acc = fmaf(R, __builtin_amdgcn_rcpf(sum), acc);
  }
  if (l < 300) op[(size_t)y * 614400 + (size_t)b * 300 + l] = 4.0f * acc;
}

// ---------------- k6c: deterministic 4-way sum -> out ----------------
__global__ __launch_bounds__(256) void k6c(const float4* __restrict__ op4,
                                           float4* __restrict__ out4) {
  int i = blockIdx.x * 256 + threadIdx.x;
  float4 a = op4[i];
  float4 b = op4[i + 153600];
  float4 c = op4[i + 307200];
  float4 d = op4[i + 460800];
  float4 r;
  r.x = ((a.x + b.x) + c.x) + d.x;
  r.y = ((a.y + b.y) + c.y) + d.y;
  r.z = ((a.z + b.z) + c.z) + d.z;
  r.w = ((a.w + b.w) + c.w) + d.w;
  out4[i] = r;
}

extern "C" void kernel_launch(void* const* d_in, const int* in_sizes, int n_in,
                              void* d_out, int out_size, void* d_ws,
                              size_t ws_size, hipStream_t stream) {
  const float* G = (const float*)d_in[0];
  const float* w1 = (const float*)d_in[1];
  const float* g1 = (const float*)d_in[3];
  const float* be1 = (const float*)d_in[4];
  const float* w2 = (const float*)d_in[5];
  const float* g2 = (const float*)d_in[7];
  const float* be2 = (const float*)d_in[8];
  const float* w3 = (const float*)d_in[9];
  const float* g3 = (const float*)d_in[11];
  const float* be3 = (const float*)d_in[12];
  const float* ct1_w = (const float*)d_in[13];
  const float* ct1_b = (const float*)d_in[14];
  const float* ct2_w = (const float*)d_in[15];
  const float* ct2_b = (const float*)d_in[16];
  const float* ct3_w = (const float*)d_in[17];
  const float* ct3_b = (const float*)d_in[18];
  const float* cf_w = (const float*)d_in[19];
  const float* cf_b = (const float*)d_in[20];
  float* out = (float*)d_out;

  float* ws = (float*)d_ws;
  // All buffers have a single deterministic writer; overlays are time-disjoint.
  float* Y2 = ws;                           // [0, 2097152)   k2 -> k4
  float* Spre = ws;                         // [0, 1638400)   k6a -> k6b (Y2 dead)
  ushort* X1thi = (ushort*)(ws + 2097152);  // [2097152, 3145728) k1c -> k2
  ushort* X1tlo = (ushort*)(ws + 3145728);  // [3145728, 4194304) k1c -> k2
  ushort* W2thi = (ushort*)(ws + 4194304);  // [4194304, 4718592) kpre -> k2
  ushort* W2tlo = (ushort*)(ws + 4718592);  // [4718592, 5242880) kpre -> k2
  float* P = ws + 2097152;                  // [2097152, 4554752) k4 -> k5a (X1t,W2thi-head dead)
  float* op = ws + 2097152;                 // same region, k6b -> k6c (P dead)
  ushort* W3hi = (ushort*)(ws + 5242880);   // [5242880, 5324800) kpre -> k4
  ushort* W3lo = (ushort*)(ws + 5324800);   // [5324800, 5406720) kpre -> k4
  float* s2p = ws + 5406720;                // [5406720, 5472256) k2 -> kc2 (dead before Y3)
  float* q2p = ws + 5472256;                // [5472256, 5537792)
  float* sA1 = ws + 5537792;                // k1s -> k1c (dead before Y3 write)
  float* qA1 = ws + 5538816;
  float* Y3 = ws + 5406720;                 // [5406720, 5713920) k5a -> k6a (overlays s2p/sA1 after dead)
  float* p3s = ws + 5713920;                // [5713920, 5754880) k5a -> k5b
  float* p3q = ws + 5754880;                // [5754880, 5795840)
  float* sA3 = ws + 5795840;                // k5b -> k6a
  float* qA3 = ws + 5796000;
  float* scale2 = ws + 5796160;             // kc2 -> k4
  float* shift2 = ws + 5797184;             // ends 5798208 (~23.2 MB)

  kpre<<<1184, 256, 0, stream>>>(w2, w3, W2thi, W2tlo, W3hi, W3lo);
  k1s<<<256, 256, 0, stream>>>(G, w1, sA1, qA1);
  k1c<<<256, 256, 0, stream>>>(G, w1, sA1, qA1, g1, be1, X1thi, X1tlo);
  k2_mfma<<<256, 512, 0, stream>>>(X1thi, X1tlo, W2thi, W2tlo, Y2, s2p, q2p);
  kc2<<<1024, 64, 0, stream>>>(s2p, q2p, g2, be2, scale2, shift2);
  k4_mfma<<<dim3(64, 8), 256, 0, stream>>>(Y2, scale2, shift2, W3hi, W3lo, P);
  k5a<<<256, 192, 0, stream>>>(P, Y3, p3s, p3q);
  k5b<<<150, 256, 0, stream>>>(p3s, p3q, sA3, qA3);
  k6a<<<512, 256, 0, stream>>>(Y3, sA3, qA3, g3, be3, ct1_w, ct1_b, ct2_w,
                               ct2_b, ct3_w, ct3_b, cf_w, cf_b, Spre);
  k6b<<<dim3(2048, 4), 320, 0, stream>>>(Spre, op);
  k6c<<<600, 256, 0, stream>>>((const float4*)op, (float4*)out);
}